// Round 4
// baseline (452.739 us; speedup 1.0000x reference)
//
#include <hip/hip_runtime.h>
#include <hip/hip_bf16.h>
#include <cstdint>

#define TSEQ 2048
#define NB   2
#define NH   16
#define NKV  4
#define HD   128
#define EMB  2048
#define WIN  512

typedef unsigned short u16;
typedef __attribute__((ext_vector_type(8))) short s16x8;
typedef __attribute__((ext_vector_type(4))) float f32x4;
typedef __attribute__((ext_vector_type(4))) unsigned short u16x4;

__device__ __forceinline__ u16 f2bf(float x) {
    unsigned u = __builtin_bit_cast(unsigned, x);
    u += 0x7fffu + ((u >> 16) & 1u);
    return (u16)(u >> 16);
}
__device__ __forceinline__ float bf2f(u16 u) {
    return __builtin_bit_cast(float, ((unsigned)u) << 16);
}
__device__ __forceinline__ float ex2(float x) {
    return __builtin_amdgcn_exp2f(x);
}

__device__ __forceinline__ void gld_lds16(const void* g, void* l) {
    __builtin_amdgcn_global_load_lds(
        (__attribute__((address_space(1))) void*)(void*)(g),
        (__attribute__((address_space(3))) void*)(l),
        16, 0, 0);
}

__device__ __forceinline__ f32x4 mfma16(s16x8 a, s16x8 b, f32x4 c) {
    return __builtin_amdgcn_mfma_f32_16x16x32_bf16(a, b, c, 0, 0, 0);
}

// ---- DPP 16-lane reductions (VALU speed, no LDS pipe) ----
template <int CTRL>
__device__ __forceinline__ float dpp_movf(float x) {
    return __builtin_bit_cast(float,
        __builtin_amdgcn_update_dpp(0, __builtin_bit_cast(int, x), CTRL, 0xF, 0xF, true));
}
__device__ __forceinline__ float dpp_max16(float x) {
    x = fmaxf(x, dpp_movf<0xB1>(x));
    x = fmaxf(x, dpp_movf<0x4E>(x));
    x = fmaxf(x, dpp_movf<0x128>(x));
    x = fmaxf(x, dpp_movf<0x124>(x));
    return x;
}
__device__ __forceinline__ float dpp_sum16(float x) {
    x += dpp_movf<0xB1>(x);
    x += dpp_movf<0x4E>(x);
    x += dpp_movf<0x128>(x);
    x += dpp_movf<0x124>(x);
    return x;
}

// ---------------- fused fp32 -> bf16 casts + rope table ----------------
// blocks [0,18432): casts; blocks [18432,18944): cos/sin table
__global__ void cast_all(const float* __restrict__ x,  const float* __restrict__ wq,
                         const float* __restrict__ wk, const float* __restrict__ wv,
                         const float* __restrict__ wo,
                         u16* __restrict__ xb, u16* __restrict__ wqb,
                         u16* __restrict__ wkvb, u16* __restrict__ wob,
                         float* __restrict__ tab) {
    if (blockIdx.x >= 18432) {
        int i = (blockIdx.x - 18432) * 256 + threadIdx.x;   // 131072 threads
        int t = i >> 6, d = i & 63;
        float inv = __expf(-(float)d * (9.210340371976184f / 64.0f));
        float s, c;
        sincosf((float)t * inv, &s, &c);
        tab[i] = c;
        tab[131072 + i] = s;
        return;
    }
    long i = ((long)blockIdx.x * 256 + threadIdx.x) * 4;
    const float* s; u16* d; long off;
    if (i < 8388608L)        { s = x;  d = xb;             off = i; }
    else if (i < 12582912L)  { s = wq; d = wqb;            off = i - 8388608L; }
    else if (i < 13631488L)  { s = wk; d = wkvb;           off = i - 12582912L; }
    else if (i < 14680064L)  { s = wv; d = wkvb + 1048576; off = i - 13631488L; }
    else                     { s = wo; d = wob;            off = i - 14680064L; }
    float4 v = *(const float4*)(s + off);
    u16x4 o;
    o[0] = f2bf(v.x); o[1] = f2bf(v.y); o[2] = f2bf(v.z); o[3] = f2bf(v.w);
    *(u16x4*)(d + off) = o;
}

// ---------------- m97-style bf16 GEMM:  C[M][N] = A[M][K] * B[N][K]^T ----------------
// MODE 0: fp32 out. MODE 1: bf16 out. MODE 2: KV fused (K->stride512, V->vt[b][kv][d][t])
template <int MODE>
__global__ __launch_bounds__(256) void gemm_bt(const u16* __restrict__ A, const u16* __restrict__ B,
                                               void* __restrict__ Cp, u16* __restrict__ vtp,
                                               int M, int N, int K) {
    __shared__ __align__(16) u16 As[128 * 32];
    __shared__ __align__(16) u16 Bs[128 * 32];
    const int tid  = threadIdx.x;
    const int lane = tid & 63;
    const int w    = tid >> 6;
    const int l15  = lane & 15;
    const int quad = lane >> 4;
    const int wr   = w >> 1, wc = w & 1;

    const int srow  = w * 32 + (lane >> 2);
    const int cbyte = (lane & 3) * 16;
    const char* ag0 = (const char*)(A + (size_t)(blockIdx.y * 128 + srow) * K) + cbyte;
    const char* ag1 = ag0 + (size_t)16 * K * 2;
    const char* bg0 = (const char*)(B + (size_t)(blockIdx.x * 128 + srow) * K) + cbyte;
    const char* bg1 = bg0 + (size_t)16 * K * 2;
    char* al0 = (char*)As + (w * 32) * 64;
    char* al1 = al0 + 16 * 64;
    char* bl0 = (char*)Bs + (w * 32) * 64;
    char* bl1 = bl0 + 16 * 64;

    f32x4 acc[4][4];
#pragma unroll
    for (int i = 0; i < 4; i++)
#pragma unroll
        for (int j = 0; j < 4; j++)
            acc[i][j] = f32x4{0.f, 0.f, 0.f, 0.f};

    for (int k0 = 0; k0 < K; k0 += 32) {
        gld_lds16(ag0, al0);
        gld_lds16(ag1, al1);
        gld_lds16(bg0, bl0);
        gld_lds16(bg1, bl1);
        ag0 += 64; ag1 += 64; bg0 += 64; bg1 += 64;
        __syncthreads();
        s16x8 af[4], bf[4];
#pragma unroll
        for (int i = 0; i < 4; i++)
            af[i] = *(const s16x8*)(As + (wr * 64 + i * 16 + l15) * 32 + quad * 8);
#pragma unroll
        for (int j = 0; j < 4; j++)
            bf[j] = *(const s16x8*)(Bs + (wc * 64 + j * 16 + l15) * 32 + quad * 8);
#pragma unroll
        for (int i = 0; i < 4; i++)
#pragma unroll
            for (int j = 0; j < 4; j++)
                acc[i][j] = mfma16(af[i], bf[j], acc[i][j]);
        __syncthreads();
    }

    const int row0 = blockIdx.y * 128 + wr * 64;
    const int col0 = blockIdx.x * 128 + wc * 64 + l15;
#pragma unroll
    for (int i = 0; i < 4; i++) {
        const int trow0 = row0 + i * 16 + quad * 4;
#pragma unroll
        for (int j = 0; j < 4; j++) {
            const int col = col0 + j * 16;
            if (MODE == 0) {
#pragma unroll
                for (int r = 0; r < 4; r++)
                    ((float*)Cp)[(size_t)(trow0 + r) * N + col] = acc[i][j][r];
            } else if (MODE == 1) {
#pragma unroll
                for (int r = 0; r < 4; r++)
                    ((u16*)Cp)[(size_t)(trow0 + r) * N + col] = f2bf(acc[i][j][r]);
            } else {
                if (col < 512) {
#pragma unroll
                    for (int r = 0; r < 4; r++)
                        ((u16*)Cp)[(size_t)(trow0 + r) * 512 + col] = f2bf(acc[i][j][r]);
                } else {
                    const int bb  = trow0 >> 11;
                    const int t0  = trow0 & (TSEQ - 1);
                    const int kvi = (col - 512) >> 7;
                    const int d   = (col - 512) & (HD - 1);
                    u16x4 pk;
#pragma unroll
                    for (int r = 0; r < 4; r++) pk[r] = f2bf(acc[i][j][r]);
                    *(u16x4*)(vtp + ((size_t)((bb * NKV + kvi) * HD + d)) * TSEQ + t0) = pk;
                }
            }
        }
    }
}

// ---------------- RoPE in-place on bf16 K via table ----------------
__global__ void rope_k(u16* __restrict__ buf, const float* __restrict__ tab) {
    int i = blockIdx.x * 256 + threadIdx.x;   // 1048576 threads
    int d   = i & 63;
    int hh  = (i >> 6) & 3;
    int row = i >> 8;
    int t   = row & (TSEQ - 1);
    size_t base = (size_t)row * 512 + hh * HD + d;
    float x1 = bf2f(buf[base]);
    float x2 = bf2f(buf[base + 64]);
    float c = tab[t * 64 + d];
    float s = tab[131072 + t * 64 + d];
    buf[base]      = f2bf(x1 * c - x2 * s);
    buf[base + 64] = f2bf(x2 * c + x1 * s);
}

// ---------------- flash attention: ONE WAVE per block = one (16-query tile, head) ----------------
// exp2-domain online softmax. Grid (128, 16, 2), block 64.
__global__ __launch_bounds__(64, 4) void attn_kernel(const u16* __restrict__ qb, const u16* __restrict__ kb,
                                                     const u16* __restrict__ vt, const float* __restrict__ tab,
                                                     u16* __restrict__ ao) {
    __shared__ __align__(16) u16 Pw[1024];      // 16x64 P tile, 2 KB
    const int lane = threadIdx.x;
    const int l15  = lane & 15;
    const int quad = lane >> 4;
    const int q0   = blockIdx.x * 16;
    const int h    = blockIdx.y;
    const int b    = blockIdx.z;
    const int kv   = h >> 2;
    const float scale2 = 0.1275174089593282f;   // (1/sqrt(128)) * log2(e)

    // ---- Q fragments with fused RoPE from table ----
    s16x8 aq[4];
    {
        const u16* qrow = qb + (size_t)(b * TSEQ + q0 + l15) * EMB + h * HD + quad * 8;
        const float* ct = tab + (size_t)(q0 + l15) * 64 + quad * 8;
        float qf[4][8], cs[2][8], sn[2][8];
        *(float4*)(&cs[0][0]) = *(const float4*)(ct);
        *(float4*)(&cs[0][4]) = *(const float4*)(ct + 4);
        *(float4*)(&cs[1][0]) = *(const float4*)(ct + 32);
        *(float4*)(&cs[1][4]) = *(const float4*)(ct + 36);
        *(float4*)(&sn[0][0]) = *(const float4*)(ct + 131072);
        *(float4*)(&sn[0][4]) = *(const float4*)(ct + 131076);
        *(float4*)(&sn[1][0]) = *(const float4*)(ct + 131104);
        *(float4*)(&sn[1][4]) = *(const float4*)(ct + 131108);
#pragma unroll
        for (int c = 0; c < 4; c++)
#pragma unroll
            for (int e = 0; e < 8; e++)
                qf[c][e] = bf2f(qrow[c * 32 + e]);
#pragma unroll
        for (int c = 0; c < 2; c++)
#pragma unroll
            for (int e = 0; e < 8; e++) {
                float x1 = qf[c][e], x2 = qf[c + 2][e];
                qf[c][e]     = x1 * cs[c][e] - x2 * sn[c][e];
                qf[c + 2][e] = x2 * cs[c][e] + x1 * sn[c][e];
            }
#pragma unroll
        for (int c = 0; c < 4; c++)
#pragma unroll
            for (int e = 0; e < 8; e++)
                aq[c][e] = (short)f2bf(qf[c][e]);
    }

    f32x4 o[8];
#pragma unroll
    for (int n = 0; n < 8; n++) o[n] = f32x4{0.f, 0.f, 0.f, 0.f};
    float mrow[4] = {-1e30f, -1e30f, -1e30f, -1e30f};   // log2 domain
    float lrow[4] = {0.f, 0.f, 0.f, 0.f};

    int kb0 = q0 - (WIN - 1);
    if (kb0 < 0) kb0 = 0;
    kb0 &= ~63;

    for (int kbi = kb0; kbi <= q0 + 15; kbi += 64) {
        // ---- K loads (16 coalesced b128) ----
        const u16* kr = kb + (size_t)(b * TSEQ + kbi + l15) * 512 + kv * HD + quad * 8;
        s16x8 bkf[4][4];
#pragma unroll
        for (int kt = 0; kt < 4; kt++)
#pragma unroll
            for (int c = 0; c < 4; c++)
                bkf[kt][c] = *(const s16x8*)(kr + kt * 16 * 512 + c * 32);

        // ---- V chunk-0 loads issued before the MFMAs wait on K ----
        const u16* vb = vt + ((size_t)(b * NKV + kv) * HD + l15) * TSEQ + kbi + quad * 8;
        s16x8 vf0[8];
#pragma unroll
        for (int n = 0; n < 8; n++)
            vf0[n] = *(const s16x8*)(vb + (size_t)n * 16 * TSEQ);

        // ---- QK^T ----
        f32x4 s[4];
#pragma unroll
        for (int kt = 0; kt < 4; kt++) s[kt] = f32x4{0.f, 0.f, 0.f, 0.f};
#pragma unroll
        for (int c = 0; c < 4; c++)
#pragma unroll
            for (int kt = 0; kt < 4; kt++)
                s[kt] = mfma16(aq[c], bkf[kt][c], s[kt]);

        // ---- online softmax in exp2 domain ----
        const bool full = (kbi >= q0 - 496) && (kbi + 63 <= q0);  // wave-uniform
        float alpha[4], p[4][4];
#pragma unroll
        for (int r = 0; r < 4; r++) {
            const int row = q0 + quad * 4 + r;
            float v[4];
            if (full) {
#pragma unroll
                for (int kt = 0; kt < 4; kt++) v[kt] = s[kt][r] * scale2;
            } else {
#pragma unroll
                for (int kt = 0; kt < 4; kt++) {
                    int cidx = kbi + kt * 16 + l15;
                    v[kt] = (cidx <= row && row - cidx < WIN) ? s[kt][r] * scale2 : -1e30f;
                }
            }
            float mx = fmaxf(fmaxf(v[0], v[1]), fmaxf(v[2], v[3]));
            mx = dpp_max16(mx);
            float mnew = fmaxf(mrow[r], mx);
            alpha[r] = ex2(mrow[r] - mnew);
            float e0 = ex2(v[0] - mnew);
            float e1 = ex2(v[1] - mnew);
            float e2 = ex2(v[2] - mnew);
            float e3 = ex2(v[3] - mnew);
            float rs = (e0 + e1) + (e2 + e3);
            rs = dpp_sum16(rs);
            lrow[r] = lrow[r] * alpha[r] + rs;
            mrow[r] = mnew;
            p[0][r] = e0; p[1][r] = e1; p[2][r] = e2; p[3][r] = e3;
        }

        // ---- V chunk-1 loads: latency hides under LDS roundtrip ----
        s16x8 vf1[8];
#pragma unroll
        for (int n = 0; n < 8; n++)
            vf1[n] = *(const s16x8*)(vb + 32 + (size_t)n * 16 * TSEQ);

#pragma unroll
        for (int n = 0; n < 8; n++) {
            o[n][0] *= alpha[0]; o[n][1] *= alpha[1];
            o[n][2] *= alpha[2]; o[n][3] *= alpha[3];
        }

        // ---- P: C-layout -> LDS -> A-layout ----
#pragma unroll
        for (int r = 0; r < 4; r++)
#pragma unroll
            for (int kt = 0; kt < 4; kt++)
                Pw[(kt >> 1) * 512 + (quad * 4 + r) * 32 + (kt & 1) * 16 + l15] = f2bf(p[kt][r]);
        asm volatile("s_waitcnt lgkmcnt(0)" ::: "memory");
        s16x8 ap0 = *(const s16x8*)(Pw + l15 * 32 + quad * 8);
        s16x8 ap1 = *(const s16x8*)(Pw + 512 + l15 * 32 + quad * 8);

        // ---- PV ----
#pragma unroll
        for (int n = 0; n < 8; n++)
            o[n] = mfma16(ap0, vf0[n], o[n]);
#pragma unroll
        for (int n = 0; n < 8; n++)
            o[n] = mfma16(ap1, vf1[n], o[n]);
    }

    // epilogue: divide by l, write bf16 attn-out in (b,t,h,d)
#pragma unroll
    for (int r = 0; r < 4; r++) {
        float inv = 1.0f / lrow[r];
#pragma unroll
        for (int n = 0; n < 8; n++)
            ao[(size_t)(b * TSEQ + q0 + quad * 4 + r) * EMB + h * HD + n * 16 + l15] =
                f2bf(o[n][r] * inv);
    }
}

extern "C" void kernel_launch(void* const* d_in, const int* in_sizes, int n_in,
                              void* d_out, int out_size, void* d_ws, size_t ws_size,
                              hipStream_t stream) {
    const float* x  = (const float*)d_in[0];
    const float* Wq = (const float*)d_in[1];
    const float* Wk = (const float*)d_in[2];
    const float* Wv = (const float*)d_in[3];
    const float* Wo = (const float*)d_in[4];
    float* out = (float*)d_out;

    u16* ws   = (u16*)d_ws;
    u16* xb   = ws;                 //  8388608  (4096 x 2048)  [reused as ao]
    u16* wqb  = ws + 8388608L;      //  4194304
    u16* wkvb = ws + 12582912L;     //  2097152  rows: Wk then Wv
    u16* wob  = ws + 14680064L;     //  4194304
    u16* qb   = ws + 18874368L;     //  8388608  raw Q (rope fused in attn)
    u16* kbuf = ws + 27262976L;     //  2097152  (4096 x 512) roped K
    u16* vt   = ws + 29360128L;     //  2097152  (b,kv,d,t)
    float* tab = (float*)(ws + 31457280L);  // 262144 floats = 1 MB (cos|sin)
    u16* ao   = xb;
    // total ws < 64 MB

    cast_all<<<18944, 256, 0, stream>>>(x, Wq, Wk, Wv, Wo, xb, wqb, wkvb, wob, tab);

    gemm_bt<1><<<dim3(16, 32), 256, 0, stream>>>(xb, wqb, qb, nullptr, 4096, 2048, 2048);
    gemm_bt<2><<<dim3(8, 32),  256, 0, stream>>>(xb, wkvb, kbuf, vt, 4096, 1024, 2048);

    rope_k<<<4096, 256, 0, stream>>>(kbuf, tab);

    attn_kernel<<<dim3(128, 16, 2), 64, 0, stream>>>(qb, kbuf, vt, tab, ao);

    gemm_bt<0><<<dim3(16, 32), 256, 0, stream>>>(ao, wob, out, nullptr, 4096, 2048, 2048);
}

// Round 5
// 430.207 us; speedup vs baseline: 1.0524x; 1.0524x over previous
//
#include <hip/hip_runtime.h>
#include <hip/hip_bf16.h>
#include <cstdint>

#define TSEQ 2048
#define NB   2
#define NH   16
#define NKV  4
#define HD   128
#define EMB  2048
#define WIN  512

typedef unsigned short u16;
typedef __attribute__((ext_vector_type(8))) short s16x8;
typedef __attribute__((ext_vector_type(4))) float f32x4;
typedef __attribute__((ext_vector_type(4))) unsigned short u16x4;

__device__ __forceinline__ u16 f2bf(float x) {
    unsigned u = __builtin_bit_cast(unsigned, x);
    u += 0x7fffu + ((u >> 16) & 1u);
    return (u16)(u >> 16);
}
__device__ __forceinline__ float bf2f(u16 u) {
    return __builtin_bit_cast(float, ((unsigned)u) << 16);
}
__device__ __forceinline__ float ex2(float x) {
    return __builtin_amdgcn_exp2f(x);
}

__device__ __forceinline__ void gld_lds16(const void* g, void* l) {
    __builtin_amdgcn_global_load_lds(
        (__attribute__((address_space(1))) void*)(void*)(g),
        (__attribute__((address_space(3))) void*)(l),
        16, 0, 0);
}

__device__ __forceinline__ f32x4 mfma16(s16x8 a, s16x8 b, f32x4 c) {
    return __builtin_amdgcn_mfma_f32_16x16x32_bf16(a, b, c, 0, 0, 0);
}

// ---- DPP 16-lane reductions (VALU speed, no LDS pipe) ----
template <int CTRL>
__device__ __forceinline__ float dpp_movf(float x) {
    return __builtin_bit_cast(float,
        __builtin_amdgcn_update_dpp(0, __builtin_bit_cast(int, x), CTRL, 0xF, 0xF, true));
}
__device__ __forceinline__ float dpp_max16(float x) {
    x = fmaxf(x, dpp_movf<0xB1>(x));
    x = fmaxf(x, dpp_movf<0x4E>(x));
    x = fmaxf(x, dpp_movf<0x128>(x));
    x = fmaxf(x, dpp_movf<0x124>(x));
    return x;
}
__device__ __forceinline__ float dpp_sum16(float x) {
    x += dpp_movf<0xB1>(x);
    x += dpp_movf<0x4E>(x);
    x += dpp_movf<0x128>(x);
    x += dpp_movf<0x124>(x);
    return x;
}

// ---------------- fused fp32 -> bf16 casts + rope table ----------------
__global__ void cast_all(const float* __restrict__ x,  const float* __restrict__ wq,
                         const float* __restrict__ wk, const float* __restrict__ wv,
                         const float* __restrict__ wo,
                         u16* __restrict__ xb, u16* __restrict__ wqb,
                         u16* __restrict__ wkvb, u16* __restrict__ wob,
                         float* __restrict__ tab) {
    if (blockIdx.x >= 18432) {
        int i = (blockIdx.x - 18432) * 256 + threadIdx.x;   // 131072 threads
        int t = i >> 6, d = i & 63;
        float inv = __expf(-(float)d * (9.210340371976184f / 64.0f));
        float s, c;
        sincosf((float)t * inv, &s, &c);
        tab[i] = c;
        tab[131072 + i] = s;
        return;
    }
    long i = ((long)blockIdx.x * 256 + threadIdx.x) * 4;
    const float* s; u16* d; long off;
    if (i < 8388608L)        { s = x;  d = xb;             off = i; }
    else if (i < 12582912L)  { s = wq; d = wqb;            off = i - 8388608L; }
    else if (i < 13631488L)  { s = wk; d = wkvb;           off = i - 12582912L; }
    else if (i < 14680064L)  { s = wv; d = wkvb + 1048576; off = i - 13631488L; }
    else                     { s = wo; d = wob;            off = i - 14680064L; }
    float4 v = *(const float4*)(s + off);
    u16x4 o;
    o[0] = f2bf(v.x); o[1] = f2bf(v.y); o[2] = f2bf(v.z); o[3] = f2bf(v.w);
    *(u16x4*)(d + off) = o;
}

// ---------------- m97-style bf16 GEMM:  C[M][N] = A[M][K] * B[N][K]^T ----------------
// MODE 0: fp32 out (stride N).
// MODE 3: fused QKV epilogue — cols<2048 -> qb (stride 2048); [2048,2560) -> kbuf (stride 512);
//         [2560,3072) -> vt[b][kv][d][t] transpose-pack.
template <int MODE>
__global__ __launch_bounds__(256) void gemm_bt(const u16* __restrict__ A, const u16* __restrict__ B,
                                               void* __restrict__ Cp, u16* __restrict__ vtp,
                                               u16* __restrict__ kp,
                                               int M, int N, int K) {
    __shared__ __align__(16) u16 As[128 * 32];
    __shared__ __align__(16) u16 Bs[128 * 32];
    const int tid  = threadIdx.x;
    const int lane = tid & 63;
    const int w    = tid >> 6;
    const int l15  = lane & 15;
    const int quad = lane >> 4;
    const int wr   = w >> 1, wc = w & 1;

    const int srow  = w * 32 + (lane >> 2);
    const int cbyte = (lane & 3) * 16;
    const char* ag0 = (const char*)(A + (size_t)(blockIdx.y * 128 + srow) * K) + cbyte;
    const char* ag1 = ag0 + (size_t)16 * K * 2;
    const char* bg0 = (const char*)(B + (size_t)(blockIdx.x * 128 + srow) * K) + cbyte;
    const char* bg1 = bg0 + (size_t)16 * K * 2;
    char* al0 = (char*)As + (w * 32) * 64;
    char* al1 = al0 + 16 * 64;
    char* bl0 = (char*)Bs + (w * 32) * 64;
    char* bl1 = bl0 + 16 * 64;

    f32x4 acc[4][4];
#pragma unroll
    for (int i = 0; i < 4; i++)
#pragma unroll
        for (int j = 0; j < 4; j++)
            acc[i][j] = f32x4{0.f, 0.f, 0.f, 0.f};

    for (int k0 = 0; k0 < K; k0 += 32) {
        gld_lds16(ag0, al0);
        gld_lds16(ag1, al1);
        gld_lds16(bg0, bl0);
        gld_lds16(bg1, bl1);
        ag0 += 64; ag1 += 64; bg0 += 64; bg1 += 64;
        __syncthreads();
        s16x8 af[4], bf[4];
#pragma unroll
        for (int i = 0; i < 4; i++)
            af[i] = *(const s16x8*)(As + (wr * 64 + i * 16 + l15) * 32 + quad * 8);
#pragma unroll
        for (int j = 0; j < 4; j++)
            bf[j] = *(const s16x8*)(Bs + (wc * 64 + j * 16 + l15) * 32 + quad * 8);
#pragma unroll
        for (int i = 0; i < 4; i++)
#pragma unroll
            for (int j = 0; j < 4; j++)
                acc[i][j] = mfma16(af[i], bf[j], acc[i][j]);
        __syncthreads();
    }

    const int row0 = blockIdx.y * 128 + wr * 64;
    const int col0 = blockIdx.x * 128 + wc * 64 + l15;
#pragma unroll
    for (int i = 0; i < 4; i++) {
        const int trow0 = row0 + i * 16 + quad * 4;
#pragma unroll
        for (int j = 0; j < 4; j++) {
            const int col = col0 + j * 16;
            if (MODE == 0) {
#pragma unroll
                for (int r = 0; r < 4; r++)
                    ((float*)Cp)[(size_t)(trow0 + r) * N + col] = acc[i][j][r];
            } else {
                if (col < 2048) {
#pragma unroll
                    for (int r = 0; r < 4; r++)
                        ((u16*)Cp)[(size_t)(trow0 + r) * 2048 + col] = f2bf(acc[i][j][r]);
                } else if (col < 2560) {
#pragma unroll
                    for (int r = 0; r < 4; r++)
                        kp[(size_t)(trow0 + r) * 512 + (col - 2048)] = f2bf(acc[i][j][r]);
                } else {
                    const int bb  = trow0 >> 11;
                    const int t0  = trow0 & (TSEQ - 1);
                    const int kvi = (col - 2560) >> 7;
                    const int d   = (col - 2560) & (HD - 1);
                    u16x4 pk;
#pragma unroll
                    for (int r = 0; r < 4; r++) pk[r] = f2bf(acc[i][j][r]);
                    *(u16x4*)(vtp + ((size_t)((bb * NKV + kvi) * HD + d)) * TSEQ + t0) = pk;
                }
            }
        }
    }
}

// ---------------- RoPE in-place on bf16 K via table ----------------
__global__ void rope_k(u16* __restrict__ buf, const float* __restrict__ tab) {
    int i = blockIdx.x * 256 + threadIdx.x;   // 1048576 threads
    int d   = i & 63;
    int hh  = (i >> 6) & 3;
    int row = i >> 8;
    int t   = row & (TSEQ - 1);
    size_t base = (size_t)row * 512 + hh * HD + d;
    float x1 = bf2f(buf[base]);
    float x2 = bf2f(buf[base + 64]);
    float c = tab[t * 64 + d];
    float s = tab[131072 + t * 64 + d];
    buf[base]      = f2bf(x1 * c - x2 * s);
    buf[base + 64] = f2bf(x2 * c + x1 * s);
}

// ---------------- flash attention, XCD-pinned swizzle ----------------
// Grid: 2048 blocks x 128 threads (2 independent waves, adjacent q-tiles).
// id&7 -> (b, kv) combo (8 combos = 8 XCDs on the %8 dispatch heuristic);
// slot = id>>3: slot&3 = q-head within kv group (innermost => 4 q-heads hit the
// same K-window back-to-back in L2), slot>>2 = 32-query tile-pair.
__global__ __launch_bounds__(128, 4) void attn_kernel(const u16* __restrict__ qb, const u16* __restrict__ kb,
                                                      const u16* __restrict__ vt, const float* __restrict__ tab,
                                                      u16* __restrict__ ao) {
    __shared__ __align__(16) u16 Pl[2048];      // per-wave 16x64 P tile
    const int w    = threadIdx.x >> 6;
    const int lane = threadIdx.x & 63;
    const int l15  = lane & 15;
    const int quad = lane >> 4;
    const int id   = blockIdx.x;
    const int kv   = id & 3;
    const int b    = (id >> 2) & 1;
    const int slot = id >> 3;
    const int h    = kv * 4 + (slot & 3);
    const int q0   = (slot >> 2) * 32 + w * 16;
    u16* Pw = Pl + w * 1024;
    const float scale2 = 0.1275174089593282f;   // (1/sqrt(128)) * log2(e)

    // ---- Q fragments with fused RoPE from table ----
    s16x8 aq[4];
    {
        const u16* qrow = qb + (size_t)(b * TSEQ + q0 + l15) * EMB + h * HD + quad * 8;
        const float* ct = tab + (size_t)(q0 + l15) * 64 + quad * 8;
        float qf[4][8], cs[2][8], sn[2][8];
        *(float4*)(&cs[0][0]) = *(const float4*)(ct);
        *(float4*)(&cs[0][4]) = *(const float4*)(ct + 4);
        *(float4*)(&cs[1][0]) = *(const float4*)(ct + 32);
        *(float4*)(&cs[1][4]) = *(const float4*)(ct + 36);
        *(float4*)(&sn[0][0]) = *(const float4*)(ct + 131072);
        *(float4*)(&sn[0][4]) = *(const float4*)(ct + 131076);
        *(float4*)(&sn[1][0]) = *(const float4*)(ct + 131104);
        *(float4*)(&sn[1][4]) = *(const float4*)(ct + 131108);
#pragma unroll
        for (int c = 0; c < 4; c++)
#pragma unroll
            for (int e = 0; e < 8; e++)
                qf[c][e] = bf2f(qrow[c * 32 + e]);
#pragma unroll
        for (int c = 0; c < 2; c++)
#pragma unroll
            for (int e = 0; e < 8; e++) {
                float x1 = qf[c][e], x2 = qf[c + 2][e];
                qf[c][e]     = x1 * cs[c][e] - x2 * sn[c][e];
                qf[c + 2][e] = x2 * cs[c][e] + x1 * sn[c][e];
            }
#pragma unroll
        for (int c = 0; c < 4; c++)
#pragma unroll
            for (int e = 0; e < 8; e++)
                aq[c][e] = (short)f2bf(qf[c][e]);
    }

    f32x4 o[8];
#pragma unroll
    for (int n = 0; n < 8; n++) o[n] = f32x4{0.f, 0.f, 0.f, 0.f};
    float mrow[4] = {-1e30f, -1e30f, -1e30f, -1e30f};   // log2 domain
    float lrow[4] = {0.f, 0.f, 0.f, 0.f};

    int kb0 = q0 - (WIN - 1);
    if (kb0 < 0) kb0 = 0;
    kb0 &= ~63;

    for (int kbi = kb0; kbi <= q0 + 15; kbi += 64) {
        // ---- K loads (16 coalesced b128) ----
        const u16* kr = kb + (size_t)(b * TSEQ + kbi + l15) * 512 + kv * HD + quad * 8;
        s16x8 bkf[4][4];
#pragma unroll
        for (int kt = 0; kt < 4; kt++)
#pragma unroll
            for (int c = 0; c < 4; c++)
                bkf[kt][c] = *(const s16x8*)(kr + kt * 16 * 512 + c * 32);

        // ---- V chunk-0 loads issued before the MFMAs wait on K ----
        const u16* vb = vt + ((size_t)(b * NKV + kv) * HD + l15) * TSEQ + kbi + quad * 8;
        s16x8 vf0[8];
#pragma unroll
        for (int n = 0; n < 8; n++)
            vf0[n] = *(const s16x8*)(vb + (size_t)n * 16 * TSEQ);

        // ---- QK^T ----
        f32x4 s[4];
#pragma unroll
        for (int kt = 0; kt < 4; kt++) s[kt] = f32x4{0.f, 0.f, 0.f, 0.f};
#pragma unroll
        for (int c = 0; c < 4; c++)
#pragma unroll
            for (int kt = 0; kt < 4; kt++)
                s[kt] = mfma16(aq[c], bkf[kt][c], s[kt]);

        // ---- online softmax in exp2 domain ----
        const bool full = (kbi >= q0 - 496) && (kbi + 63 <= q0);  // wave-uniform
        float alpha[4], p[4][4];
#pragma unroll
        for (int r = 0; r < 4; r++) {
            const int row = q0 + quad * 4 + r;
            float v[4];
            if (full) {
#pragma unroll
                for (int kt = 0; kt < 4; kt++) v[kt] = s[kt][r] * scale2;
            } else {
#pragma unroll
                for (int kt = 0; kt < 4; kt++) {
                    int cidx = kbi + kt * 16 + l15;
                    v[kt] = (cidx <= row && row - cidx < WIN) ? s[kt][r] * scale2 : -1e30f;
                }
            }
            float mx = fmaxf(fmaxf(v[0], v[1]), fmaxf(v[2], v[3]));
            mx = dpp_max16(mx);
            float mnew = fmaxf(mrow[r], mx);
            alpha[r] = ex2(mrow[r] - mnew);
            float e0 = ex2(v[0] - mnew);
            float e1 = ex2(v[1] - mnew);
            float e2 = ex2(v[2] - mnew);
            float e3 = ex2(v[3] - mnew);
            float rs = (e0 + e1) + (e2 + e3);
            rs = dpp_sum16(rs);
            lrow[r] = lrow[r] * alpha[r] + rs;
            mrow[r] = mnew;
            p[0][r] = e0; p[1][r] = e1; p[2][r] = e2; p[3][r] = e3;
        }

        // ---- V chunk-1 loads: latency hides under LDS roundtrip ----
        s16x8 vf1[8];
#pragma unroll
        for (int n = 0; n < 8; n++)
            vf1[n] = *(const s16x8*)(vb + 32 + (size_t)n * 16 * TSEQ);

#pragma unroll
        for (int n = 0; n < 8; n++) {
            o[n][0] *= alpha[0]; o[n][1] *= alpha[1];
            o[n][2] *= alpha[2]; o[n][3] *= alpha[3];
        }

        // ---- P: C-layout -> LDS -> A-layout ----
#pragma unroll
        for (int r = 0; r < 4; r++)
#pragma unroll
            for (int kt = 0; kt < 4; kt++)
                Pw[(kt >> 1) * 512 + (quad * 4 + r) * 32 + (kt & 1) * 16 + l15] = f2bf(p[kt][r]);
        asm volatile("s_waitcnt lgkmcnt(0)" ::: "memory");
        s16x8 ap0 = *(const s16x8*)(Pw + l15 * 32 + quad * 8);
        s16x8 ap1 = *(const s16x8*)(Pw + 512 + l15 * 32 + quad * 8);

        // ---- PV ----
#pragma unroll
        for (int n = 0; n < 8; n++)
            o[n] = mfma16(ap0, vf0[n], o[n]);
#pragma unroll
        for (int n = 0; n < 8; n++)
            o[n] = mfma16(ap1, vf1[n], o[n]);
    }

    // epilogue: divide by l, write bf16 attn-out in (b,t,h,d)
#pragma unroll
    for (int r = 0; r < 4; r++) {
        float inv = 1.0f / lrow[r];
#pragma unroll
        for (int n = 0; n < 8; n++)
            ao[(size_t)(b * TSEQ + q0 + quad * 4 + r) * EMB + h * HD + n * 16 + l15] =
                f2bf(o[n][r] * inv);
    }
}

extern "C" void kernel_launch(void* const* d_in, const int* in_sizes, int n_in,
                              void* d_out, int out_size, void* d_ws, size_t ws_size,
                              hipStream_t stream) {
    const float* x  = (const float*)d_in[0];
    const float* Wq = (const float*)d_in[1];
    const float* Wk = (const float*)d_in[2];
    const float* Wv = (const float*)d_in[3];
    const float* Wo = (const float*)d_in[4];
    float* out = (float*)d_out;

    u16* ws   = (u16*)d_ws;
    u16* xb   = ws;                 //  8388608  (4096 x 2048)  [reused as ao]
    u16* wqb  = ws + 8388608L;      //  4194304  } adjacent: Wq|Wk|Wv = 3072 x 2048
    u16* wkvb = ws + 12582912L;     //  2097152  }
    u16* wob  = ws + 14680064L;     //  4194304
    u16* qb   = ws + 18874368L;     //  8388608  raw Q (rope fused in attn)
    u16* kbuf = ws + 27262976L;     //  2097152  (4096 x 512) roped K
    u16* vt   = ws + 29360128L;     //  2097152  (b,kv,d,t)
    float* tab = (float*)(ws + 31457280L);  // 262144 floats = 1 MB (cos|sin)
    u16* ao   = xb;
    // total ws < 64 MB

    cast_all<<<18944, 256, 0, stream>>>(x, Wq, Wk, Wv, Wo, xb, wqb, wkvb, wob, tab);

    // fused QKV projection: B = [Wq|Wk|Wv] (3072 x 2048), 768 blocks = 3/CU
    gemm_bt<3><<<dim3(24, 32), 256, 0, stream>>>(xb, wqb, qb, vt, kbuf, 4096, 3072, 2048);

    rope_k<<<4096, 256, 0, stream>>>(kbuf, tab);

    attn_kernel<<<2048, 128, 0, stream>>>(qb, kbuf, vt, tab, ao);

    gemm_bt<0><<<dim3(16, 32), 256, 0, stream>>>(ao, wob, out, nullptr, nullptr, 4096, 2048, 2048);
}

// Round 7
// 287.642 us; speedup vs baseline: 1.5740x; 1.4956x over previous
//
#include <hip/hip_runtime.h>
#include <hip/hip_bf16.h>
#include <cstdint>

#define TSEQ 2048
#define NB   2
#define NH   16
#define NKV  4
#define HD   128
#define EMB  2048
#define WIN  512

typedef unsigned short u16;
typedef __attribute__((ext_vector_type(8))) short s16x8;
typedef __attribute__((ext_vector_type(4))) float f32x4;
typedef __attribute__((ext_vector_type(4))) unsigned short u16x4;
typedef __attribute__((ext_vector_type(8))) unsigned short u16x8;

__device__ __forceinline__ u16 f2bf(float x) {
    unsigned u = __builtin_bit_cast(unsigned, x);
    u += 0x7fffu + ((u >> 16) & 1u);
    return (u16)(u >> 16);
}
__device__ __forceinline__ float bf2f(u16 u) {
    return __builtin_bit_cast(float, ((unsigned)u) << 16);
}
__device__ __forceinline__ float ex2(float x) {
    return __builtin_amdgcn_exp2f(x);
}

__device__ __forceinline__ void gld_lds16(const void* g, void* l) {
    __builtin_amdgcn_global_load_lds(
        (__attribute__((address_space(1))) void*)(void*)(g),
        (__attribute__((address_space(3))) void*)(l),
        16, 0, 0);
}

__device__ __forceinline__ f32x4 mfma16(s16x8 a, s16x8 b, f32x4 c) {
    return __builtin_amdgcn_mfma_f32_16x16x32_bf16(a, b, c, 0, 0, 0);
}

// ---- DPP 16-lane reductions ----
template <int CTRL>
__device__ __forceinline__ float dpp_movf(float x) {
    return __builtin_bit_cast(float,
        __builtin_amdgcn_update_dpp(0, __builtin_bit_cast(int, x), CTRL, 0xF, 0xF, true));
}
__device__ __forceinline__ float dpp_max16(float x) {
    x = fmaxf(x, dpp_movf<0xB1>(x));
    x = fmaxf(x, dpp_movf<0x4E>(x));
    x = fmaxf(x, dpp_movf<0x128>(x));
    x = fmaxf(x, dpp_movf<0x124>(x));
    return x;
}
__device__ __forceinline__ float dpp_sum16(float x) {
    x += dpp_movf<0xB1>(x);
    x += dpp_movf<0x4E>(x);
    x += dpp_movf<0x128>(x);
    x += dpp_movf<0x124>(x);
    return x;
}

// ---------------- fused fp32 -> bf16 casts + rope table ----------------
__global__ void cast_all(const float* __restrict__ x,  const float* __restrict__ wq,
                         const float* __restrict__ wk, const float* __restrict__ wv,
                         const float* __restrict__ wo,
                         u16* __restrict__ xb, u16* __restrict__ wqb,
                         u16* __restrict__ wkvb, u16* __restrict__ wob,
                         float* __restrict__ tab) {
    if (blockIdx.x >= 18432) {
        int i = (blockIdx.x - 18432) * 256 + threadIdx.x;   // 131072 threads
        int t = i >> 6, d = i & 63;
        float inv = __expf(-(float)d * (9.210340371976184f / 64.0f));
        float s, c;
        sincosf((float)t * inv, &s, &c);
        tab[i] = c;
        tab[131072 + i] = s;
        return;
    }
    long i = ((long)blockIdx.x * 256 + threadIdx.x) * 4;
    const float* s; u16* d; long off;
    if (i < 8388608L)        { s = x;  d = xb;             off = i; }
    else if (i < 12582912L)  { s = wq; d = wqb;            off = i - 8388608L; }
    else if (i < 13631488L)  { s = wk; d = wkvb;           off = i - 12582912L; }
    else if (i < 14680064L)  { s = wv; d = wkvb + 1048576; off = i - 13631488L; }
    else                     { s = wo; d = wob;            off = i - 14680064L; }
    float4 v = *(const float4*)(s + off);
    u16x4 o;
    o[0] = f2bf(v.x); o[1] = f2bf(v.y); o[2] = f2bf(v.z); o[3] = f2bf(v.w);
    *(u16x4*)(d + off) = o;
}

// ---------------- m97-style bf16 GEMM:  C[M][N] = A[M][K] * B[N][K]^T ----------------
// MODE 0: fp32 out (stride N).
// MODE 3: fused QKV — blocks x<16: Q->Cp stride 2048; x 16..19: K->kp stride 512;
//         x 20..23: V -> LDS-transposed -> vt[b][kv][d][t] (coalesced 256B segments).
template <int MODE>
__global__ __launch_bounds__(256) void gemm_bt(const u16* __restrict__ A, const u16* __restrict__ B,
                                               void* __restrict__ Cp, u16* __restrict__ vtp,
                                               u16* __restrict__ kp,
                                               int M, int N, int K) {
    __shared__ __align__(16) char smem[MODE == 3 ? 17408 : 16384];
    u16* As = (u16*)smem;
    u16* Bs = As + 4096;
    const int tid  = threadIdx.x;
    const int lane = tid & 63;
    const int w    = tid >> 6;
    const int l15  = lane & 15;
    const int quad = lane >> 4;
    const int wr   = w >> 1, wc = w & 1;

    const int srow  = w * 32 + (lane >> 2);
    const int cbyte = (lane & 3) * 16;
    const char* ag0 = (const char*)(A + (size_t)(blockIdx.y * 128 + srow) * K) + cbyte;
    const char* ag1 = ag0 + (size_t)16 * K * 2;
    const char* bg0 = (const char*)(B + (size_t)(blockIdx.x * 128 + srow) * K) + cbyte;
    const char* bg1 = bg0 + (size_t)16 * K * 2;
    char* al0 = (char*)As + (w * 32) * 64;
    char* al1 = al0 + 16 * 64;
    char* bl0 = (char*)Bs + (w * 32) * 64;
    char* bl1 = bl0 + 16 * 64;

    f32x4 acc[4][4];
#pragma unroll
    for (int i = 0; i < 4; i++)
#pragma unroll
        for (int j = 0; j < 4; j++)
            acc[i][j] = f32x4{0.f, 0.f, 0.f, 0.f};

    for (int k0 = 0; k0 < K; k0 += 32) {
        gld_lds16(ag0, al0);
        gld_lds16(ag1, al1);
        gld_lds16(bg0, bl0);
        gld_lds16(bg1, bl1);
        ag0 += 64; ag1 += 64; bg0 += 64; bg1 += 64;
        __syncthreads();
        s16x8 af[4], bf[4];
#pragma unroll
        for (int i = 0; i < 4; i++)
            af[i] = *(const s16x8*)(As + (wr * 64 + i * 16 + l15) * 32 + quad * 8);
#pragma unroll
        for (int j = 0; j < 4; j++)
            bf[j] = *(const s16x8*)(Bs + (wc * 64 + j * 16 + l15) * 32 + quad * 8);
#pragma unroll
        for (int i = 0; i < 4; i++)
#pragma unroll
            for (int j = 0; j < 4; j++)
                acc[i][j] = mfma16(af[i], bf[j], acc[i][j]);
        __syncthreads();
    }

    const int row0 = blockIdx.y * 128 + wr * 64;
    const int col0 = blockIdx.x * 128 + wc * 64 + l15;

    if (MODE == 0) {
#pragma unroll
        for (int i = 0; i < 4; i++)
#pragma unroll
            for (int j = 0; j < 4; j++)
#pragma unroll
                for (int r = 0; r < 4; r++)
                    ((float*)Cp)[(size_t)(row0 + i * 16 + quad * 4 + r) * N + col0 + j * 16] =
                        acc[i][j][r];
    } else {
        if (blockIdx.x < 16) {
#pragma unroll
            for (int i = 0; i < 4; i++)
#pragma unroll
                for (int j = 0; j < 4; j++)
#pragma unroll
                    for (int r = 0; r < 4; r++)
                        ((u16*)Cp)[(size_t)(row0 + i * 16 + quad * 4 + r) * 2048 + col0 + j * 16] =
                            f2bf(acc[i][j][r]);
        } else if (blockIdx.x < 20) {
            const int kcol0 = col0 - 2048;
#pragma unroll
            for (int i = 0; i < 4; i++)
#pragma unroll
                for (int j = 0; j < 4; j++)
#pragma unroll
                    for (int r = 0; r < 4; r++)
                        kp[(size_t)(row0 + i * 16 + quad * 4 + r) * 512 + kcol0 + j * 16] =
                            f2bf(acc[i][j][r]);
        } else {
            // V: transpose through LDS (stride 136 u16 -> 16B-aligned b128 rows),
            // write vt[b][kv][d][t] as 256B row segments
            const int kvi  = blockIdx.x - 20;
            const int bb   = (blockIdx.y * 128) >> 11;
            const int tl0  = (blockIdx.y * 128) & (TSEQ - 1);
            u16* tr = (u16*)smem;   // 64 x 136
#pragma unroll
            for (int p = 0; p < 2; p++) {
                __syncthreads();
                if (wc == p) {
#pragma unroll
                    for (int i = 0; i < 4; i++)
#pragma unroll
                        for (int j = 0; j < 4; j++)
#pragma unroll
                            for (int r = 0; r < 4; r++)
                                tr[(j * 16 + l15) * 136 + wr * 64 + i * 16 + quad * 4 + r] =
                                    f2bf(acc[i][j][r]);
                }
                __syncthreads();
#pragma unroll
                for (int s = 0; s < 4; s++) {
                    int slot = s * 256 + tid;
                    int dr = slot >> 4;
                    int tc = slot & 15;
                    u16x8 val = *(const u16x8*)(tr + dr * 136 + tc * 8);
                    *(u16x8*)(vtp + ((size_t)((bb * NKV + kvi) * HD + p * 64 + dr)) * TSEQ +
                              tl0 + tc * 8) = val;
                }
            }
        }
    }
}

// ---------------- RoPE in-place on bf16 K via table ----------------
__global__ void rope_k(u16* __restrict__ buf, const float* __restrict__ tab) {
    int i = blockIdx.x * 256 + threadIdx.x;   // 1048576 threads
    int d   = i & 63;
    int hh  = (i >> 6) & 3;
    int row = i >> 8;
    int t   = row & (TSEQ - 1);
    size_t base = (size_t)row * 512 + hh * HD + d;
    float x1 = bf2f(buf[base]);
    float x2 = bf2f(buf[base + 64]);
    float c = tab[t * 64 + d];
    float s = tab[131072 + t * 64 + d];
    buf[base]      = f2bf(x1 * c - x2 * s);
    buf[base + 64] = f2bf(x2 * c + x1 * s);
}

// ---------------- flash attention: block = (b, kv, 16-q tile), 4 waves = 4 q-heads ----------------
// K/V tiles staged once per block into LDS (swizzled), shared by all 4 waves.
// Grid 1024 x 256; id&7 -> (b,kv) for XCD pinning; id>>3 -> q-tile.
__global__ __launch_bounds__(256, 3) void attn_kernel(const u16* __restrict__ qb, const u16* __restrict__ kb,
                                                      const u16* __restrict__ vt, const float* __restrict__ tab,
                                                      u16* __restrict__ ao) {
    __shared__ __align__(16) char smem[40960];
    u16* ks = (u16*)smem;              // 64 keys x 128 d  (16 KB), chunk-swizzled
    u16* vs = (u16*)(smem + 16384);    // 128 d x 64 keys (16 KB), chunk-swizzled
    u16* Pl = (u16*)(smem + 32768);    // 4 x 2 KB per-wave P tiles (16x64 bf16 each)

    const int tid  = threadIdx.x;
    const int w    = tid >> 6;
    const int lane = tid & 63;
    const int l15  = lane & 15;
    const int quad = lane >> 4;
    const int id   = blockIdx.x;
    const int kv   = id & 3;
    const int b    = (id >> 2) & 1;
    const int q0   = (id >> 3) * 16;
    const int h    = kv * 4 + w;
    u16* Pw = Pl + w * 1024;           // 1024 u16 = 2 KB per wave (FIX: was w*512 -> race)
    const float scale2 = 0.1275174089593282f;   // (1/sqrt(128)) * log2(e)

    const u16* kbase = kb + (size_t)b * TSEQ * 512 + kv * HD;
    const u16* vbase = vt + (size_t)(b * NKV + kv) * HD * TSEQ;

    // ---- Q fragments with fused RoPE from table ----
    s16x8 aq[4];
    {
        const u16* qrow = qb + (size_t)(b * TSEQ + q0 + l15) * EMB + h * HD + quad * 8;
        const float* ct = tab + (size_t)(q0 + l15) * 64 + quad * 8;
        float qf[4][8], cs[2][8], sn[2][8];
        *(float4*)(&cs[0][0]) = *(const float4*)(ct);
        *(float4*)(&cs[0][4]) = *(const float4*)(ct + 4);
        *(float4*)(&cs[1][0]) = *(const float4*)(ct + 32);
        *(float4*)(&cs[1][4]) = *(const float4*)(ct + 36);
        *(float4*)(&sn[0][0]) = *(const float4*)(ct + 131072);
        *(float4*)(&sn[0][4]) = *(const float4*)(ct + 131076);
        *(float4*)(&sn[1][0]) = *(const float4*)(ct + 131104);
        *(float4*)(&sn[1][4]) = *(const float4*)(ct + 131108);
#pragma unroll
        for (int c = 0; c < 4; c++)
#pragma unroll
            for (int e = 0; e < 8; e++)
                qf[c][e] = bf2f(qrow[c * 32 + e]);
#pragma unroll
        for (int c = 0; c < 2; c++)
#pragma unroll
            for (int e = 0; e < 8; e++) {
                float x1 = qf[c][e], x2 = qf[c + 2][e];
                qf[c][e]     = x1 * cs[c][e] - x2 * sn[c][e];
                qf[c + 2][e] = x2 * cs[c][e] + x1 * sn[c][e];
            }
#pragma unroll
        for (int c = 0; c < 4; c++)
#pragma unroll
            for (int e = 0; e < 8; e++)
                aq[c][e] = (short)f2bf(qf[c][e]);
    }

    f32x4 o[8];
#pragma unroll
    for (int n = 0; n < 8; n++) o[n] = f32x4{0.f, 0.f, 0.f, 0.f};
    float mrow[4] = {-1e30f, -1e30f, -1e30f, -1e30f};   // log2 domain
    float lrow[4] = {0.f, 0.f, 0.f, 0.f};

    int kb0 = q0 - (WIN - 1);
    if (kb0 < 0) kb0 = 0;
    kb0 &= ~63;

    for (int kbi = kb0; kbi <= q0 + 15; kbi += 64) {
        // ---- stage K (64x128) and V^T (128x64) into LDS, chunk-swizzled ----
#pragma unroll
        for (int s = 0; s < 4; s++) {
            int slot = s * 256 + tid;
            int i    = slot >> 4;
            int lc   = (slot & 15) ^ (i & 7);
            gld_lds16(kbase + (size_t)(kbi + i) * 512 + lc * 8, (char*)ks + slot * 16);
        }
#pragma unroll
        for (int s = 0; s < 4; s++) {
            int slot = s * 256 + tid;
            int d    = slot >> 3;
            int lc   = (slot & 7) ^ (d & 7);
            gld_lds16(vbase + (size_t)d * TSEQ + kbi + lc * 8, (char*)vs + slot * 16);
        }
        __syncthreads();

        // ---- QK^T from LDS ----
        f32x4 sv[4];
#pragma unroll
        for (int kt = 0; kt < 4; kt++) sv[kt] = f32x4{0.f, 0.f, 0.f, 0.f};
#pragma unroll
        for (int c = 0; c < 4; c++) {
            s16x8 bk[4];
#pragma unroll
            for (int kt = 0; kt < 4; kt++) {
                int sc = (c * 4 + quad) ^ (l15 & 7);
                bk[kt] = *(const s16x8*)(ks + (kt * 16 + l15) * 128 + sc * 8);
            }
#pragma unroll
            for (int kt = 0; kt < 4; kt++)
                sv[kt] = mfma16(aq[c], bk[kt], sv[kt]);
        }

        // ---- online softmax in exp2 domain ----
        const bool full = (kbi >= q0 - 496) && (kbi + 63 <= q0);  // block-uniform
        float alpha[4], p[4][4];
#pragma unroll
        for (int r = 0; r < 4; r++) {
            const int row = q0 + quad * 4 + r;
            float v[4];
            if (full) {
#pragma unroll
                for (int kt = 0; kt < 4; kt++) v[kt] = sv[kt][r] * scale2;
            } else {
#pragma unroll
                for (int kt = 0; kt < 4; kt++) {
                    int cidx = kbi + kt * 16 + l15;
                    v[kt] = (cidx <= row && row - cidx < WIN) ? sv[kt][r] * scale2 : -1e30f;
                }
            }
            float mx = fmaxf(fmaxf(v[0], v[1]), fmaxf(v[2], v[3]));
            mx = dpp_max16(mx);
            float mnew = fmaxf(mrow[r], mx);
            alpha[r] = ex2(mrow[r] - mnew);
            float e0 = ex2(v[0] - mnew);
            float e1 = ex2(v[1] - mnew);
            float e2 = ex2(v[2] - mnew);
            float e3 = ex2(v[3] - mnew);
            float rs = (e0 + e1) + (e2 + e3);
            rs = dpp_sum16(rs);
            lrow[r] = lrow[r] * alpha[r] + rs;
            mrow[r] = mnew;
            p[0][r] = e0; p[1][r] = e1; p[2][r] = e2; p[3][r] = e3;
        }
#pragma unroll
        for (int n = 0; n < 8; n++) {
            o[n][0] *= alpha[0]; o[n][1] *= alpha[1];
            o[n][2] *= alpha[2]; o[n][3] *= alpha[3];
        }

        // ---- P: C-layout -> LDS -> A-layout (per-wave private 2KB region) ----
#pragma unroll
        for (int r = 0; r < 4; r++)
#pragma unroll
            for (int kt = 0; kt < 4; kt++)
                Pw[(kt >> 1) * 512 + (quad * 4 + r) * 32 + (kt & 1) * 16 + l15] = f2bf(p[kt][r]);
        asm volatile("s_waitcnt lgkmcnt(0)" ::: "memory");
        s16x8 ap0 = *(const s16x8*)(Pw + l15 * 32 + quad * 8);
        s16x8 ap1 = *(const s16x8*)(Pw + 512 + l15 * 32 + quad * 8);

        // ---- PV from LDS V^T ----
#pragma unroll
        for (int n = 0; n < 8; n++) {
            int sc = quad ^ (l15 & 7);
            s16x8 bv = *(const s16x8*)(vs + (n * 16 + l15) * 64 + sc * 8);
            o[n] = mfma16(ap0, bv, o[n]);
        }
#pragma unroll
        for (int n = 0; n < 8; n++) {
            int sc = (4 + quad) ^ (l15 & 7);
            s16x8 bv = *(const s16x8*)(vs + (n * 16 + l15) * 64 + sc * 8);
            o[n] = mfma16(ap1, bv, o[n]);
        }
        __syncthreads();
    }

    // ---- epilogue: LDS transpose (stride 136 -> aligned b128) -> coalesced stores ----
    float linv[4];
#pragma unroll
    for (int r = 0; r < 4; r++) linv[r] = 1.0f / lrow[r];
    u16* Ow = (u16*)(smem + w * 4352);   // 16 x 136 u16 = 4352 B, per-wave
#pragma unroll
    for (int n = 0; n < 8; n++)
#pragma unroll
        for (int r = 0; r < 4; r++)
            Ow[(quad * 4 + r) * 136 + n * 16 + l15] = f2bf(o[n][r] * linv[r]);
    asm volatile("s_waitcnt lgkmcnt(0)" ::: "memory");
#pragma unroll
    for (int s = 0; s < 4; s++) {
        int row = s * 4 + quad;
        u16x8 val = *(const u16x8*)(Ow + row * 136 + l15 * 8);
        *(u16x8*)(ao + (size_t)(b * TSEQ + q0 + row) * EMB + h * HD + l15 * 8) = val;
    }
}

extern "C" void kernel_launch(void* const* d_in, const int* in_sizes, int n_in,
                              void* d_out, int out_size, void* d_ws, size_t ws_size,
                              hipStream_t stream) {
    const float* x  = (const float*)d_in[0];
    const float* Wq = (const float*)d_in[1];
    const float* Wk = (const float*)d_in[2];
    const float* Wv = (const float*)d_in[3];
    const float* Wo = (const float*)d_in[4];
    float* out = (float*)d_out;

    u16* ws   = (u16*)d_ws;
    u16* xb   = ws;                 //  8388608  (4096 x 2048)  [reused as ao]
    u16* wqb  = ws + 8388608L;      //  4194304  } adjacent: Wq|Wk|Wv = 3072 x 2048
    u16* wkvb = ws + 12582912L;     //  2097152  }
    u16* wob  = ws + 14680064L;     //  4194304
    u16* qb   = ws + 18874368L;     //  8388608  raw Q (rope fused in attn)
    u16* kbuf = ws + 27262976L;     //  2097152  (4096 x 512) roped K
    u16* vt   = ws + 29360128L;     //  2097152  (b,kv,d,t)
    float* tab = (float*)(ws + 31457280L);  // 262144 floats = 1 MB (cos|sin)
    u16* ao   = xb;
    // total ws < 64 MB

    cast_all<<<18944, 256, 0, stream>>>(x, Wq, Wk, Wv, Wo, xb, wqb, wkvb, wob, tab);

    // fused QKV projection: B = [Wq|Wk|Wv] (3072 x 2048)
    gemm_bt<3><<<dim3(24, 32), 256, 0, stream>>>(xb, wqb, qb, vt, kbuf, 4096, 3072, 2048);

    rope_k<<<4096, 256, 0, stream>>>(kbuf, tab);

    attn_kernel<<<1024, 256, 0, stream>>>(qb, kbuf, vt, tab, ao);

    gemm_bt<0><<<dim3(16, 32), 256, 0, stream>>>(ao, wob, out, nullptr, nullptr, 4096, 2048, 2048);
}

// Round 8
// 267.840 us; speedup vs baseline: 1.6903x; 1.0739x over previous
//
#include <hip/hip_runtime.h>
#include <hip/hip_bf16.h>
#include <cstdint>

#define TSEQ 2048
#define NB   2
#define NH   16
#define NKV  4
#define HD   128
#define EMB  2048
#define WIN  512

typedef unsigned short u16;
typedef __attribute__((ext_vector_type(8))) short s16x8;
typedef __attribute__((ext_vector_type(4))) float f32x4;
typedef __attribute__((ext_vector_type(16))) float f32x16;
typedef __attribute__((ext_vector_type(4))) unsigned short u16x4;
typedef __attribute__((ext_vector_type(8))) unsigned short u16x8;

__device__ __forceinline__ u16 f2bf(float x) {
    unsigned u = __builtin_bit_cast(unsigned, x);
    u += 0x7fffu + ((u >> 16) & 1u);
    return (u16)(u >> 16);
}
__device__ __forceinline__ float bf2f(u16 u) {
    return __builtin_bit_cast(float, ((unsigned)u) << 16);
}
__device__ __forceinline__ float ex2(float x) {
    return __builtin_amdgcn_exp2f(x);
}

__device__ __forceinline__ void gld_lds16(const void* g, void* l) {
    __builtin_amdgcn_global_load_lds(
        (__attribute__((address_space(1))) void*)(void*)(g),
        (__attribute__((address_space(3))) void*)(l),
        16, 0, 0);
}

__device__ __forceinline__ f32x4 mfma16(s16x8 a, s16x8 b, f32x4 c) {
    return __builtin_amdgcn_mfma_f32_16x16x32_bf16(a, b, c, 0, 0, 0);
}
__device__ __forceinline__ f32x16 mfma32(s16x8 a, s16x8 b, f32x16 c) {
    return __builtin_amdgcn_mfma_f32_32x32x16_bf16(a, b, c, 0, 0, 0);
}

// ---- DPP 16-lane reductions ----
template <int CTRL>
__device__ __forceinline__ float dpp_movf(float x) {
    return __builtin_bit_cast(float,
        __builtin_amdgcn_update_dpp(0, __builtin_bit_cast(int, x), CTRL, 0xF, 0xF, true));
}
__device__ __forceinline__ float dpp_max16(float x) {
    x = fmaxf(x, dpp_movf<0xB1>(x));
    x = fmaxf(x, dpp_movf<0x4E>(x));
    x = fmaxf(x, dpp_movf<0x128>(x));
    x = fmaxf(x, dpp_movf<0x124>(x));
    return x;
}
__device__ __forceinline__ float dpp_sum16(float x) {
    x += dpp_movf<0xB1>(x);
    x += dpp_movf<0x4E>(x);
    x += dpp_movf<0x128>(x);
    x += dpp_movf<0x124>(x);
    return x;
}

// ---------------- fused fp32 -> bf16 casts + rope table ----------------
__global__ void cast_all(const float* __restrict__ x,  const float* __restrict__ wq,
                         const float* __restrict__ wk, const float* __restrict__ wv,
                         const float* __restrict__ wo,
                         u16* __restrict__ xb, u16* __restrict__ wqb,
                         u16* __restrict__ wkvb, u16* __restrict__ wob,
                         float* __restrict__ tab) {
    if (blockIdx.x >= 18432) {
        int i = (blockIdx.x - 18432) * 256 + threadIdx.x;   // 131072 threads
        int t = i >> 6, d = i & 63;
        float inv = __expf(-(float)d * (9.210340371976184f / 64.0f));
        float s, c;
        sincosf((float)t * inv, &s, &c);
        tab[i] = c;
        tab[131072 + i] = s;
        return;
    }
    long i = ((long)blockIdx.x * 256 + threadIdx.x) * 4;
    const float* s; u16* d; long off;
    if (i < 8388608L)        { s = x;  d = xb;             off = i; }
    else if (i < 12582912L)  { s = wq; d = wqb;            off = i - 8388608L; }
    else if (i < 13631488L)  { s = wk; d = wkvb;           off = i - 12582912L; }
    else if (i < 14680064L)  { s = wv; d = wkvb + 1048576; off = i - 13631488L; }
    else                     { s = wo; d = wob;            off = i - 14680064L; }
    float4 v = *(const float4*)(s + off);
    u16x4 o;
    o[0] = f2bf(v.x); o[1] = f2bf(v.y); o[2] = f2bf(v.z); o[3] = f2bf(v.w);
    *(u16x4*)(d + off) = o;
}

// ---------------- bf16 GEMM, 32x32x16 MFMA, BK=64:  C[M][N] = A[M][K] * B[N][K]^T ----
// Block 128x128, 4 waves 2x2, wave tile 64x64 = 2x2 MFMA tiles of 32x32.
// LDS rows are 128B; XOR chunk swizzle sig(row)=((row>>1)^(row>>2))&7 applied on the
// GLOBAL source side of global_load_lds (LDS dest stays lane-contiguous). Reader
// fetches chunk c at slot c^sig(row). Max 4-way read conflict (vs 8-way in m97 layout).
// MODE 0: fp32 out (stride N).
// MODE 3: fused QKV — blocks x<16: Q->Cp stride 2048; x 16..19: K->kp stride 512;
//         x 20..23: V -> LDS-transposed -> vt[b][kv][d][t] (coalesced 256B segments).
template <int MODE>
__global__ __launch_bounds__(256) void gemm_bt(const u16* __restrict__ A, const u16* __restrict__ B,
                                               void* __restrict__ Cp, u16* __restrict__ vtp,
                                               u16* __restrict__ kp,
                                               int M, int N, int K) {
    __shared__ __align__(16) u16 smem[16384];   // As 128x64 | Bs 128x64
    u16* As = smem;
    u16* Bs = smem + 8192;
    const int tid  = threadIdx.x;
    const int lane = tid & 63;
    const int w    = tid >> 6;
    const int l31  = lane & 31;
    const int half = lane >> 5;
    const int wr   = w >> 1, wc = w & 1;

    // ---- staging pointers: call s covers rows s*32 + w*8 + (lane>>3), chunk lane&7 ----
    const int srow   = w * 8 + (lane >> 3);
    const int schunk = lane & 7;
    const u16* agp[4];
    const u16* bgp[4];
#pragma unroll
    for (int s = 0; s < 4; s++) {
        const int row = s * 32 + srow;
        const int sig = ((row >> 1) ^ (row >> 2)) & 7;
        agp[s] = A + (size_t)(blockIdx.y * 128 + row) * K + (schunk ^ sig) * 8;
        bgp[s] = B + (size_t)(blockIdx.x * 128 + row) * K + (schunk ^ sig) * 8;
    }

    // ---- loop-invariant read swizzles: frag row per (i/j) tile ----
    int sigA[2], sigB[2];
#pragma unroll
    for (int i = 0; i < 2; i++) {
        const int ra = wr * 64 + i * 32 + l31;
        sigA[i] = ((ra >> 1) ^ (ra >> 2)) & 7;
        const int rb = wc * 64 + i * 32 + l31;
        sigB[i] = ((rb >> 1) ^ (rb >> 2)) & 7;
    }

    f32x16 acc[2][2];
#pragma unroll
    for (int i = 0; i < 2; i++)
#pragma unroll
        for (int j = 0; j < 2; j++)
#pragma unroll
            for (int r = 0; r < 16; r++)
                acc[i][j][r] = 0.f;

    for (int k0 = 0; k0 < K; k0 += 64) {
#pragma unroll
        for (int s = 0; s < 4; s++) {
            gld_lds16(agp[s], (char*)As + (s * 32 + w * 8) * 128);
            agp[s] += 64;
        }
#pragma unroll
        for (int s = 0; s < 4; s++) {
            gld_lds16(bgp[s], (char*)Bs + (s * 32 + w * 8) * 128);
            bgp[s] += 64;
        }
        __syncthreads();
        s16x8 af[2][4], bf[2][4];
#pragma unroll
        for (int i = 0; i < 2; i++)
#pragma unroll
            for (int ks = 0; ks < 4; ks++)
                af[i][ks] = *(const s16x8*)((char*)As + (wr * 64 + i * 32 + l31) * 128 +
                                            ((half + ks * 2) ^ sigA[i]) * 16);
#pragma unroll
        for (int j = 0; j < 2; j++)
#pragma unroll
            for (int ks = 0; ks < 4; ks++)
                bf[j][ks] = *(const s16x8*)((char*)Bs + (wc * 64 + j * 32 + l31) * 128 +
                                            ((half + ks * 2) ^ sigB[j]) * 16);
#pragma unroll
        for (int ks = 0; ks < 4; ks++)
#pragma unroll
            for (int i = 0; i < 2; i++)
#pragma unroll
                for (int j = 0; j < 2; j++)
                    acc[i][j] = mfma32(af[i][ks], bf[j][ks], acc[i][j]);
        __syncthreads();
    }

    const int row0 = blockIdx.y * 128 + wr * 64;
    const int col0 = blockIdx.x * 128 + wc * 64 + l31;

    if (MODE == 0) {
#pragma unroll
        for (int i = 0; i < 2; i++)
#pragma unroll
            for (int j = 0; j < 2; j++)
#pragma unroll
                for (int r = 0; r < 16; r++) {
                    const int crow = row0 + i * 32 + (r & 3) + 8 * (r >> 2) + 4 * half;
                    ((float*)Cp)[(size_t)crow * N + col0 + j * 32] = acc[i][j][r];
                }
    } else {
        if (blockIdx.x < 16) {
#pragma unroll
            for (int i = 0; i < 2; i++)
#pragma unroll
                for (int j = 0; j < 2; j++)
#pragma unroll
                    for (int r = 0; r < 16; r++) {
                        const int crow = row0 + i * 32 + (r & 3) + 8 * (r >> 2) + 4 * half;
                        ((u16*)Cp)[(size_t)crow * 2048 + col0 + j * 32] = f2bf(acc[i][j][r]);
                    }
        } else if (blockIdx.x < 20) {
            const int kcol0 = col0 - 2048;
#pragma unroll
            for (int i = 0; i < 2; i++)
#pragma unroll
                for (int j = 0; j < 2; j++)
#pragma unroll
                    for (int r = 0; r < 16; r++) {
                        const int crow = row0 + i * 32 + (r & 3) + 8 * (r >> 2) + 4 * half;
                        kp[(size_t)crow * 512 + kcol0 + j * 32] = f2bf(acc[i][j][r]);
                    }
        } else {
            // V: transpose through LDS (64 x 136 u16, 16B-aligned rows), write
            // vt[b][kv][d][t] as 256B row segments.
            const int kvi = blockIdx.x - 20;
            const int bb  = (blockIdx.y * 128) >> 11;
            const int tl0 = (blockIdx.y * 128) & (TSEQ - 1);
            u16* tr = smem;   // 64 x 136 u16 = 17408 B <= 32 KB
#pragma unroll
            for (int p = 0; p < 2; p++) {
                __syncthreads();
                if (wc == p) {
#pragma unroll
                    for (int i = 0; i < 2; i++)
#pragma unroll
                        for (int j = 0; j < 2; j++)
#pragma unroll
                            for (int r = 0; r < 16; r++) {
                                const int tl = wr * 64 + i * 32 + (r & 3) + 8 * (r >> 2) + 4 * half;
                                tr[(j * 32 + l31) * 136 + tl] = f2bf(acc[i][j][r]);
                            }
                }
                __syncthreads();
#pragma unroll
                for (int s = 0; s < 4; s++) {
                    int slot = s * 256 + tid;
                    int dr = slot >> 4;
                    int tc = slot & 15;
                    u16x8 val = *(const u16x8*)(tr + dr * 136 + tc * 8);
                    *(u16x8*)(vtp + ((size_t)((bb * NKV + kvi) * HD + p * 64 + dr)) * TSEQ +
                              tl0 + tc * 8) = val;
                }
            }
        }
    }
}

// ---------------- RoPE in-place on bf16 K via table ----------------
__global__ void rope_k(u16* __restrict__ buf, const float* __restrict__ tab) {
    int i = blockIdx.x * 256 + threadIdx.x;   // 1048576 threads
    int d   = i & 63;
    int hh  = (i >> 6) & 3;
    int row = i >> 8;
    int t   = row & (TSEQ - 1);
    size_t base = (size_t)row * 512 + hh * HD + d;
    float x1 = bf2f(buf[base]);
    float x2 = bf2f(buf[base + 64]);
    float c = tab[t * 64 + d];
    float s = tab[131072 + t * 64 + d];
    buf[base]      = f2bf(x1 * c - x2 * s);
    buf[base + 64] = f2bf(x2 * c + x1 * s);
}

// ---------------- flash attention: block = (b, kv, 16-q tile), 4 waves = 4 q-heads ----------------
__global__ __launch_bounds__(256, 3) void attn_kernel(const u16* __restrict__ qb, const u16* __restrict__ kb,
                                                      const u16* __restrict__ vt, const float* __restrict__ tab,
                                                      u16* __restrict__ ao) {
    __shared__ __align__(16) char smem[40960];
    u16* ks = (u16*)smem;              // 64 keys x 128 d  (16 KB), chunk-swizzled
    u16* vs = (u16*)(smem + 16384);    // 128 d x 64 keys (16 KB), chunk-swizzled
    u16* Pl = (u16*)(smem + 32768);    // 4 x 2 KB per-wave P tiles (16x64 bf16 each)

    const int tid  = threadIdx.x;
    const int w    = tid >> 6;
    const int lane = tid & 63;
    const int l15  = lane & 15;
    const int quad = lane >> 4;
    const int id   = blockIdx.x;
    const int kv   = id & 3;
    const int b    = (id >> 2) & 1;
    const int q0   = (id >> 3) * 16;
    const int h    = kv * 4 + w;
    u16* Pw = Pl + w * 1024;
    const float scale2 = 0.1275174089593282f;   // (1/sqrt(128)) * log2(e)

    const u16* kbase = kb + (size_t)b * TSEQ * 512 + kv * HD;
    const u16* vbase = vt + (size_t)(b * NKV + kv) * HD * TSEQ;

    // ---- Q fragments with fused RoPE from table ----
    s16x8 aq[4];
    {
        const u16* qrow = qb + (size_t)(b * TSEQ + q0 + l15) * EMB + h * HD + quad * 8;
        const float* ct = tab + (size_t)(q0 + l15) * 64 + quad * 8;
        float qf[4][8], cs[2][8], sn[2][8];
        *(float4*)(&cs[0][0]) = *(const float4*)(ct);
        *(float4*)(&cs[0][4]) = *(const float4*)(ct + 4);
        *(float4*)(&cs[1][0]) = *(const float4*)(ct + 32);
        *(float4*)(&cs[1][4]) = *(const float4*)(ct + 36);
        *(float4*)(&sn[0][0]) = *(const float4*)(ct + 131072);
        *(float4*)(&sn[0][4]) = *(const float4*)(ct + 131076);
        *(float4*)(&sn[1][0]) = *(const float4*)(ct + 131104);
        *(float4*)(&sn[1][4]) = *(const float4*)(ct + 131108);
#pragma unroll
        for (int c = 0; c < 4; c++)
#pragma unroll
            for (int e = 0; e < 8; e++)
                qf[c][e] = bf2f(qrow[c * 32 + e]);
#pragma unroll
        for (int c = 0; c < 2; c++)
#pragma unroll
            for (int e = 0; e < 8; e++) {
                float x1 = qf[c][e], x2 = qf[c + 2][e];
                qf[c][e]     = x1 * cs[c][e] - x2 * sn[c][e];
                qf[c + 2][e] = x2 * cs[c][e] + x1 * sn[c][e];
            }
#pragma unroll
        for (int c = 0; c < 4; c++)
#pragma unroll
            for (int e = 0; e < 8; e++)
                aq[c][e] = (short)f2bf(qf[c][e]);
    }

    f32x4 o[8];
#pragma unroll
    for (int n = 0; n < 8; n++) o[n] = f32x4{0.f, 0.f, 0.f, 0.f};
    float mrow[4] = {-1e30f, -1e30f, -1e30f, -1e30f};   // log2 domain
    float lrow[4] = {0.f, 0.f, 0.f, 0.f};

    int kb0 = q0 - (WIN - 1);
    if (kb0 < 0) kb0 = 0;
    kb0 &= ~63;

    for (int kbi = kb0; kbi <= q0 + 15; kbi += 64) {
        // ---- stage K (64x128) and V^T (128x64) into LDS, chunk-swizzled ----
#pragma unroll
        for (int s = 0; s < 4; s++) {
            int slot = s * 256 + tid;
            int i    = slot >> 4;
            int lc   = (slot & 15) ^ (i & 7);
            gld_lds16(kbase + (size_t)(kbi + i) * 512 + lc * 8, (char*)ks + slot * 16);
        }
#pragma unroll
        for (int s = 0; s < 4; s++) {
            int slot = s * 256 + tid;
            int d    = slot >> 3;
            int lc   = (slot & 7) ^ (d & 7);
            gld_lds16(vbase + (size_t)d * TSEQ + kbi + lc * 8, (char*)vs + slot * 16);
        }
        __syncthreads();

        // ---- QK^T from LDS ----
        f32x4 sv[4];
#pragma unroll
        for (int kt = 0; kt < 4; kt++) sv[kt] = f32x4{0.f, 0.f, 0.f, 0.f};
#pragma unroll
        for (int c = 0; c < 4; c++) {
            s16x8 bk[4];
#pragma unroll
            for (int kt = 0; kt < 4; kt++) {
                int sc = (c * 4 + quad) ^ (l15 & 7);
                bk[kt] = *(const s16x8*)(ks + (kt * 16 + l15) * 128 + sc * 8);
            }
#pragma unroll
            for (int kt = 0; kt < 4; kt++)
                sv[kt] = mfma16(aq[c], bk[kt], sv[kt]);
        }

        // ---- online softmax in exp2 domain ----
        const bool full = (kbi >= q0 - 496) && (kbi + 63 <= q0);  // block-uniform
        float alpha[4], p[4][4];
#pragma unroll
        for (int r = 0; r < 4; r++) {
            const int row = q0 + quad * 4 + r;
            float v[4];
            if (full) {
#pragma unroll
                for (int kt = 0; kt < 4; kt++) v[kt] = sv[kt][r] * scale2;
            } else {
#pragma unroll
                for (int kt = 0; kt < 4; kt++) {
                    int cidx = kbi + kt * 16 + l15;
                    v[kt] = (cidx <= row && row - cidx < WIN) ? sv[kt][r] * scale2 : -1e30f;
                }
            }
            float mx = fmaxf(fmaxf(v[0], v[1]), fmaxf(v[2], v[3]));
            mx = dpp_max16(mx);
            float mnew = fmaxf(mrow[r], mx);
            alpha[r] = ex2(mrow[r] - mnew);
            float e0 = ex2(v[0] - mnew);
            float e1 = ex2(v[1] - mnew);
            float e2 = ex2(v[2] - mnew);
            float e3 = ex2(v[3] - mnew);
            float rs = (e0 + e1) + (e2 + e3);
            rs = dpp_sum16(rs);
            lrow[r] = lrow[r] * alpha[r] + rs;
            mrow[r] = mnew;
            p[0][r] = e0; p[1][r] = e1; p[2][r] = e2; p[3][r] = e3;
        }
#pragma unroll
        for (int n = 0; n < 8; n++) {
            o[n][0] *= alpha[0]; o[n][1] *= alpha[1];
            o[n][2] *= alpha[2]; o[n][3] *= alpha[3];
        }

        // ---- P: C-layout -> LDS -> A-layout (per-wave private 2KB region) ----
#pragma unroll
        for (int r = 0; r < 4; r++)
#pragma unroll
            for (int kt = 0; kt < 4; kt++)
                Pw[(kt >> 1) * 512 + (quad * 4 + r) * 32 + (kt & 1) * 16 + l15] = f2bf(p[kt][r]);
        asm volatile("s_waitcnt lgkmcnt(0)" ::: "memory");
        s16x8 ap0 = *(const s16x8*)(Pw + l15 * 32 + quad * 8);
        s16x8 ap1 = *(const s16x8*)(Pw + 512 + l15 * 32 + quad * 8);

        // ---- PV from LDS V^T ----
#pragma unroll
        for (int n = 0; n < 8; n++) {
            int sc = quad ^ (l15 & 7);
            s16x8 bv = *(const s16x8*)(vs + (n * 16 + l15) * 64 + sc * 8);
            o[n] = mfma16(ap0, bv, o[n]);
        }
#pragma unroll
        for (int n = 0; n < 8; n++) {
            int sc = (4 + quad) ^ (l15 & 7);
            s16x8 bv = *(const s16x8*)(vs + (n * 16 + l15) * 64 + sc * 8);
            o[n] = mfma16(ap1, bv, o[n]);
        }
        __syncthreads();
    }

    // ---- epilogue: LDS transpose (stride 136 -> aligned b128) -> coalesced stores ----
    float linv[4];
#pragma unroll
    for (int r = 0; r < 4; r++) linv[r] = 1.0f / lrow[r];
    u16* Ow = (u16*)(smem + w * 4352);   // 16 x 136 u16 = 4352 B, per-wave
#pragma unroll
    for (int n = 0; n < 8; n++)
#pragma unroll
        for (int r = 0; r < 4; r++)
            Ow[(quad * 4 + r) * 136 + n * 16 + l15] = f2bf(o[n][r] * linv[r]);
    asm volatile("s_waitcnt lgkmcnt(0)" ::: "memory");
#pragma unroll
    for (int s = 0; s < 4; s++) {
        int row = s * 4 + quad;
        u16x8 val = *(const u16x8*)(Ow + row * 136 + l15 * 8);
        *(u16x8*)(ao + (size_t)(b * TSEQ + q0 + row) * EMB + h * HD + l15 * 8) = val;
    }
}

extern "C" void kernel_launch(void* const* d_in, const int* in_sizes, int n_in,
                              void* d_out, int out_size, void* d_ws, size_t ws_size,
                              hipStream_t stream) {
    const float* x  = (const float*)d_in[0];
    const float* Wq = (const float*)d_in[1];
    const float* Wk = (const float*)d_in[2];
    const float* Wv = (const float*)d_in[3];
    const float* Wo = (const float*)d_in[4];
    float* out = (float*)d_out;

    u16* ws   = (u16*)d_ws;
    u16* xb   = ws;                 //  8388608  (4096 x 2048)  [reused as ao]
    u16* wqb  = ws + 8388608L;      //  4194304  } adjacent: Wq|Wk|Wv = 3072 x 2048
    u16* wkvb = ws + 12582912L;     //  2097152  }
    u16* wob  = ws + 14680064L;     //  4194304
    u16* qb   = ws + 18874368L;     //  8388608  raw Q (rope fused in attn)
    u16* kbuf = ws + 27262976L;     //  2097152  (4096 x 512) roped K
    u16* vt   = ws + 29360128L;     //  2097152  (b,kv,d,t)
    float* tab = (float*)(ws + 31457280L);  // 262144 floats = 1 MB (cos|sin)
    u16* ao   = xb;
    // total ws < 64 MB

    cast_all<<<18944, 256, 0, stream>>>(x, Wq, Wk, Wv, Wo, xb, wqb, wkvb, wob, tab);

    // fused QKV projection: B = [Wq|Wk|Wv] (3072 x 2048)
    gemm_bt<3><<<dim3(24, 32), 256, 0, stream>>>(xb, wqb, qb, vt, kbuf, 4096, 3072, 2048);

    rope_k<<<4096, 256, 0, stream>>>(kbuf, tab);

    attn_kernel<<<1024, 256, 0, stream>>>(qb, kbuf, vt, tab, ao);

    gemm_bt<0><<<dim3(16, 32), 256, 0, stream>>>(ao, wob, out, nullptr, nullptr, 4096, 2048, 2048);
}